// Round 4
// baseline (268.819 us; speedup 1.0000x reference)
//
#include <hip/hip_runtime.h>
#include <math.h>

#define B_  32
#define NN  10
#define QS  128
#define KS  256
#define CHW  524288   // 512*32*32
#define CHW4 131072   // CHW/4
#define BLKS_PER_B 64
#define CHUNK 16384   // BLKS_PER_B * 256 threads
#define NCHUNK 8      // CHW4 / CHUNK

typedef float f4 __attribute__((ext_vector_type(4)));

// Kernel 1: per-b attention weights (tiny; unchanged).
__global__ __launch_bounds__(256) void attn_weights_kernel(
    const float* __restrict__ qu, const float* __restrict__ kin,
    const float* __restrict__ W, const float* __restrict__ bias,
    float* __restrict__ app_out)
{
    const int b = blockIdx.x;
    const int t = threadIdx.x;

    __shared__ __align__(16) float s_qu[NN * QS];
    __shared__ __align__(16) float s_k[NN * KS];
    __shared__ __align__(16) float s_query[NN * KS];
    __shared__ float s_attn[NN * NN];

    for (int i = t; i < NN * QS; i += 256) s_qu[i] = qu[(size_t)b * NN * QS + i];
    for (int i = t; i < NN * KS; i += 256) s_k[i]  = kin[(size_t)b * NN * KS + i];
    __syncthreads();

    {
        float acc[NN];
        const float bv = bias[t];
        #pragma unroll
        for (int n = 0; n < NN; ++n) acc[n] = bv;
        const float4* wrow = (const float4*)(W + (size_t)t * QS);
        const float4* qu4  = (const float4*)s_qu;
        for (int q4 = 0; q4 < QS / 4; ++q4) {
            const float4 w = wrow[q4];
            #pragma unroll
            for (int n = 0; n < NN; ++n) {
                const float4 u = qu4[n * (QS / 4) + q4];
                acc[n] += w.x * u.x + w.y * u.y + w.z * u.z + w.w * u.w;
            }
        }
        #pragma unroll
        for (int n = 0; n < NN; ++n) s_query[n * KS + t] = acc[n];
    }
    __syncthreads();

    if (t < NN * NN) {
        const int i = t / NN, j = t % NN;
        float s = 0.f;
        for (int d = 0; d < KS; ++d) s += s_k[i * KS + d] * s_query[j * KS + d];
        s_attn[i * NN + j] = s;
    }
    __syncthreads();

    if (t < NN) {
        const int j = t;
        float m = -1e30f;
        #pragma unroll
        for (int i = 0; i < NN; ++i)
            if (i != j) m = fmaxf(m, s_attn[i * NN + j]);
        float denom = 0.f;
        #pragma unroll
        for (int i = 0; i < NN; ++i)
            if (i != j) denom += expf(s_attn[i * NN + j] - m);
        const float inv = 1.f / denom;
        #pragma unroll
        for (int i = 0; i < NN; ++i) {
            const float a = (i == j) ? 0.f : expf(s_attn[i * NN + j] - m) * inv;
            app_out[(size_t)b * NN * NN + i * NN + j] = a;
        }
    }
}

__device__ __forceinline__ void load_chunk(f4* vv, const f4* __restrict__ vb, int pos) {
    #pragma unroll
    for (int kk = 0; kk < NN; ++kk)
        vv[kk] = __builtin_nontemporal_load(&vb[(size_t)kk * CHW4 + pos]);
}

__device__ __forceinline__ void compute_store(const f4* vv, const float* s_app,
                                              f4* __restrict__ ob, int pos) {
    #pragma unroll
    for (int q = 0; q < NN; ++q) {
        f4 acc = (f4)(0.f);
        #pragma unroll
        for (int kk = 0; kk < NN; ++kk) {
            const float a = s_app[kk * NN + q];
            acc.x += a * vv[kk].x;
            acc.y += a * vv[kk].y;
            acc.z += a * vv[kk].z;
            acc.w += a * vv[kk].w;
        }
        __builtin_nontemporal_store(acc, &ob[(size_t)q * CHW4 + pos]);
    }
}

// Kernel 2: out[b,q,pos] = sum_k app[b,k,q] * v[b,k,pos]
// Persistent-per-b blocks, static double-buffered prefetch pipeline:
// next chunk's 10 loads stay in flight while current chunk's FMAs+stores run.
__global__ __launch_bounds__(256) void wsum_kernel(
    const f4* __restrict__ v, const float* __restrict__ app,
    f4* __restrict__ out)
{
    const int b      = blockIdx.x >> 6;   // 0..31
    const int blkInB = blockIdx.x & 63;   // 0..63

    __shared__ float s_app[NN * NN];
    if (threadIdx.x < NN * NN) s_app[threadIdx.x] = app[(size_t)b * NN * NN + threadIdx.x];
    __syncthreads();

    const size_t base = (size_t)b * NN * CHW4;
    const f4* vb = v   + base;
    f4*       ob = out + base;
    const int pos0 = blkInB * 256 + threadIdx.x;   // + c*CHUNK, c in [0,8)

    f4 vvA[NN], vvB[NN];   // two named buffers, all indexing compile-time (rule #20)
    load_chunk(vvA, vb, pos0);

    #pragma unroll
    for (int c = 0; c < NCHUNK; c += 2) {
        load_chunk(vvB, vb, pos0 + (c + 1) * CHUNK);
        compute_store(vvA, s_app, ob, pos0 + c * CHUNK);
        if (c + 2 < NCHUNK) load_chunk(vvA, vb, pos0 + (c + 2) * CHUNK);
        compute_store(vvB, s_app, ob, pos0 + (c + 1) * CHUNK);
    }
}

extern "C" void kernel_launch(void* const* d_in, const int* in_sizes, int n_in,
                              void* d_out, int out_size, void* d_ws, size_t ws_size,
                              hipStream_t stream) {
    const float* qu   = (const float*)d_in[0];
    const float* k    = (const float*)d_in[1];
    const float* v    = (const float*)d_in[2];
    const float* W    = (const float*)d_in[3];
    const float* bias = (const float*)d_in[4];

    float* out = (float*)d_out;
    float* app = out + (size_t)B_ * NN * CHW;  // second tuple output, flat after `out`

    attn_weights_kernel<<<B_, 256, 0, stream>>>(qu, k, W, bias, app);
    wsum_kernel<<<B_ * BLKS_PER_B, 256, 0, stream>>>((const f4*)v, app, (f4*)out);
}